// Round 1
// baseline (500.141 us; speedup 1.0000x reference)
//
#include <hip/hip_runtime.h>
#include <hip/hip_bf16.h>

#define BB 4
#define SS 2048
#define DD 1024
#define SCALE 0.03125f   // 1/sqrt(1024)

typedef __attribute__((ext_vector_type(8))) short bf16x8;
typedef __attribute__((ext_vector_type(4))) float f32x4;
typedef __attribute__((ext_vector_type(4))) float float4v;
typedef __attribute__((ext_vector_type(4))) short short4v;

__device__ __forceinline__ unsigned short f2bf(float x){
    unsigned u = __float_as_uint(x);
    return (unsigned short)((u + 0x7fffu + ((u >> 16) & 1u)) >> 16);  // RNE
}

// ---------------- prepass: f32 -> bf16 elementwise (for K) ----------------
__global__ void conv_bf16_kernel(const float* __restrict__ in,
                                 unsigned short* __restrict__ out, int n4){
    int i = blockIdx.x * 256 + threadIdx.x;
    if (i >= n4) return;
    float4v v = ((const float4v*)in)[i];
    short4v o;
    o[0] = (short)f2bf(v[0]); o[1] = (short)f2bf(v[1]);
    o[2] = (short)f2bf(v[2]); o[3] = (short)f2bf(v[3]);
    ((short4v*)out)[i] = o;
}

// ---------------- prepass: V [b][s][d] f32 -> Vt [b][d][s] bf16 ----------------
__global__ void transpose_v_kernel(const float* __restrict__ v,
                                   unsigned short* __restrict__ vt){
    __shared__ float tile[64][65];
    const int b  = blockIdx.z;
    const int s0 = blockIdx.x << 6;
    const int d0 = blockIdx.y << 6;
    const int tx = threadIdx.x & 15;
    const int ty = threadIdx.x >> 4;
#pragma unroll
    for (int kk = 0; kk < 4; ++kk){
        const float* p = v + ((b * SS + s0 + ty + 16 * kk) * DD) + d0 + tx * 4;
        float4v val = *(const float4v*)p;
        tile[ty + 16 * kk][tx * 4 + 0] = val[0];
        tile[ty + 16 * kk][tx * 4 + 1] = val[1];
        tile[ty + 16 * kk][tx * 4 + 2] = val[2];
        tile[ty + 16 * kk][tx * 4 + 3] = val[3];
    }
    __syncthreads();
#pragma unroll
    for (int kk = 0; kk < 4; ++kk){
        int dy = ty + 16 * kk;
        short4v o;
        o[0] = (short)f2bf(tile[tx * 4 + 0][dy]);
        o[1] = (short)f2bf(tile[tx * 4 + 1][dy]);
        o[2] = (short)f2bf(tile[tx * 4 + 2][dy]);
        o[3] = (short)f2bf(tile[tx * 4 + 3][dy]);
        *(short4v*)&vt[((b * DD + d0 + dy) * SS) + s0 + tx * 4] = o;
    }
}

// ---------------- fused attention + layernorm ----------------
// grid: B * (S/16) = 512 blocks, 512 threads (8 waves).
// Wave w owns d-slice [w*128, w*128+128) for QK^T partials and PV output.
__global__ __launch_bounds__(512, 4) void attn_ln_kernel(
    const float* __restrict__ qf,
    const unsigned short* __restrict__ Kb,   // [B][S][D] bf16
    const unsigned short* __restrict__ Vt,   // [B][D][S] bf16
    const int* __restrict__ mask,            // [B][S][S]
    const float* __restrict__ gamma,
    const float* __restrict__ beta,
    float* __restrict__ out)
{
    __shared__ f32x4 sred[8][2][64];          // 16 KB  S-partials
    __shared__ unsigned short plds[16][32];   // 1 KB   P tile (bf16)
    __shared__ float rs_lds[2][16];
    __shared__ float lnred[8][16][2];

    const int tid  = threadIdx.x;
    const int wid  = tid >> 6;
    const int lane = tid & 63;
    const int l16  = lane & 15;
    const int g4   = lane >> 4;
    const int b    = blockIdx.x >> 7;          // 128 q-blocks per batch
    const int q0   = (blockIdx.x & 127) << 4;

    // ---- load Q fragments (f32 -> bf16 in-register), rows q0+l16, d-slice of this wave
    bf16x8 qfrag[4];
    {
        const float* qp = qf + ((b * SS + q0 + l16) * DD) + wid * 128 + g4 * 8;
#pragma unroll
        for (int c = 0; c < 4; ++c){
            float4v a0 = *(const float4v*)(qp + c * 32);
            float4v a1 = *(const float4v*)(qp + c * 32 + 4);
            bf16x8 t;
            t[0] = (short)f2bf(a0[0]); t[1] = (short)f2bf(a0[1]);
            t[2] = (short)f2bf(a0[2]); t[3] = (short)f2bf(a0[3]);
            t[4] = (short)f2bf(a1[0]); t[5] = (short)f2bf(a1[1]);
            t[6] = (short)f2bf(a1[2]); t[7] = (short)f2bf(a1[3]);
            qfrag[c] = t;
        }
    }

    f32x4 acc[8];
    const f32x4 zero4 = {0.f, 0.f, 0.f, 0.f};
#pragma unroll
    for (int g = 0; g < 8; ++g) acc[g] = zero4;
    float rs_reg[4] = {0.f, 0.f, 0.f, 0.f};

    const int kbase = (b * SS) * DD + wid * 128 + g4 * 8;   // + kvrow*DD + c*32
    const int vbase = (b * DD + wid * 128) * SS + g4 * 8;   // + dloc*SS + kv0

    for (int kv0 = 0; kv0 < SS; kv0 += 32){
        // ---- phase 1: QK^T partial over this wave's 128-d slice
        f32x4 sp0 = zero4, sp1 = zero4;
#pragma unroll
        for (int c = 0; c < 4; ++c){
            const unsigned short* kp = Kb + kbase + (kv0 + l16) * DD + c * 32;
            bf16x8 k0 = *(const bf16x8*)kp;
            bf16x8 k1 = *(const bf16x8*)(kp + 16 * DD);
            sp0 = __builtin_amdgcn_mfma_f32_16x16x32_bf16(qfrag[c], k0, sp0, 0, 0, 0);
            sp1 = __builtin_amdgcn_mfma_f32_16x16x32_bf16(qfrag[c], k1, sp1, 0, 0, 0);
        }
        sred[wid][0][lane] = sp0;
        sred[wid][1][lane] = sp1;
        __syncthreads();

        // ---- phase 2: reduce partials, mask, exp, rowsum, write P (waves 0,1)
        if (wid < 2){
            f32x4 s = sred[0][wid][lane];
#pragma unroll
            for (int w = 1; w < 8; ++w) s += sred[w][wid][lane];
            const int mrow0 = ((b * SS + q0 + g4 * 4) * SS) + kv0 + wid * 16 + l16;
#pragma unroll
            for (int r = 0; r < 4; ++r){
                int m = mask[mrow0 + r * SS];
                float e = m ? __expf(s[r] * SCALE) : 0.f;
                float v = e;
                v += __shfl_xor(v, 1); v += __shfl_xor(v, 2);
                v += __shfl_xor(v, 4); v += __shfl_xor(v, 8);
                rs_reg[r] += v;
                plds[g4 * 4 + r][wid * 16 + l16] = f2bf(e);
            }
        }
        __syncthreads();

        // ---- phase 3: PV for this wave's 128-d slice
        bf16x8 pfrag = *(const bf16x8*)&plds[l16][g4 * 8];
        const unsigned short* vp = Vt + vbase + kv0;
#pragma unroll
        for (int g = 0; g < 8; ++g){
            bf16x8 vf = *(const bf16x8*)(vp + (g * 16 + l16) * SS);
            acc[g] = __builtin_amdgcn_mfma_f32_16x16x32_bf16(pfrag, vf, acc[g], 0, 0, 0);
        }
    }

    // ---- epilogue: rowsum finalize
    if (wid < 2 && l16 == 0){
#pragma unroll
        for (int r = 0; r < 4; ++r) rs_lds[wid][g4 * 4 + r] = rs_reg[r];
    }
    __syncthreads();

    float inv[4];
#pragma unroll
    for (int r = 0; r < 4; ++r)
        inv[r] = 1.f / (rs_lds[0][g4 * 4 + r] + rs_lds[1][g4 * 4 + r]);

    // LayerNorm partials over this wave's 128 d's
    float sx[4] = {0.f,0.f,0.f,0.f}, sxx[4] = {0.f,0.f,0.f,0.f};
#pragma unroll
    for (int g = 0; g < 8; ++g){
#pragma unroll
        for (int r = 0; r < 4; ++r){
            float x = acc[g][r] * inv[r];
            sx[r] += x; sxx[r] += x * x;
        }
    }
#pragma unroll
    for (int r = 0; r < 4; ++r){
        sx[r]  += __shfl_xor(sx[r], 1);  sx[r]  += __shfl_xor(sx[r], 2);
        sx[r]  += __shfl_xor(sx[r], 4);  sx[r]  += __shfl_xor(sx[r], 8);
        sxx[r] += __shfl_xor(sxx[r], 1); sxx[r] += __shfl_xor(sxx[r], 2);
        sxx[r] += __shfl_xor(sxx[r], 4); sxx[r] += __shfl_xor(sxx[r], 8);
    }
    if (l16 == 0){
#pragma unroll
        for (int r = 0; r < 4; ++r){
            lnred[wid][g4 * 4 + r][0] = sx[r];
            lnred[wid][g4 * 4 + r][1] = sxx[r];
        }
    }
    __syncthreads();

    float mean[4], rstd[4];
#pragma unroll
    for (int r = 0; r < 4; ++r){
        float a = 0.f, b2 = 0.f;
#pragma unroll
        for (int w = 0; w < 8; ++w){ a += lnred[w][g4 * 4 + r][0]; b2 += lnred[w][g4 * 4 + r][1]; }
        float mu = a * (1.f / 1024.f);
        float var = b2 * (1.f / 1024.f) - mu * mu;
        mean[r] = mu;
        rstd[r] = rsqrtf(var + 1e-5f);
    }

#pragma unroll
    for (int g = 0; g < 8; ++g){
        int d = wid * 128 + g * 16 + l16;
        float gm = gamma[d], bt = beta[d];
#pragma unroll
        for (int r = 0; r < 4; ++r){
            float x = acc[g][r] * inv[r];
            out[(b * SS + q0 + g4 * 4 + r) * DD + d] = (x - mean[r]) * rstd[r] * gm + bt;
        }
    }
}

extern "C" void kernel_launch(void* const* d_in, const int* in_sizes, int n_in,
                              void* d_out, int out_size, void* d_ws, size_t ws_size,
                              hipStream_t stream) {
    const float* q     = (const float*)d_in[0];
    const float* k     = (const float*)d_in[1];
    const float* v     = (const float*)d_in[2];
    const int*   mask  = (const int*)d_in[3];
    const float* gamma = (const float*)d_in[4];
    const float* beta  = (const float*)d_in[5];
    float* out = (float*)d_out;

    unsigned short* Kb = (unsigned short*)d_ws;          // 16 MB
    unsigned short* Vt = Kb + (size_t)BB * SS * DD;      // 16 MB

    const int n4 = BB * SS * DD / 4;                     // 2,097,152
    conv_bf16_kernel<<<n4 / 256, 256, 0, stream>>>(k, Kb, n4);
    dim3 tg(SS / 64, DD / 64, BB);
    transpose_v_kernel<<<tg, 256, 0, stream>>>(v, Vt);

    attn_ln_kernel<<<BB * (SS / 16), 512, 0, stream>>>(q, Kb, Vt, mask, gamma, beta, out);
}

// Round 2
// 162.930 us; speedup vs baseline: 3.0697x; 3.0697x over previous
//
#include <hip/hip_runtime.h>
#include <hip/hip_bf16.h>

typedef unsigned short u16;
typedef __attribute__((ext_vector_type(8))) short bf16x8;
typedef __attribute__((ext_vector_type(4))) float f32x4;
typedef __attribute__((ext_vector_type(4))) float float4v;
typedef __attribute__((ext_vector_type(4))) short short4v;

#define BB 4
#define SS 2048
#define DD 1024
#define SCALE 0.03125f   // 1/sqrt(1024)

__device__ __forceinline__ u16 f2bf(float x){
    unsigned u = __float_as_uint(x);
    return (u16)((u + 0x7fffu + ((u >> 16) & 1u)) >> 16);  // RNE
}

#define GLD16(g, l) __builtin_amdgcn_global_load_lds( \
    (const __attribute__((address_space(1))) unsigned int*)(g), \
    (__attribute__((address_space(3))) unsigned int*)(l), 16, 0, 0)

// ---------------- prepass: f32 -> bf16 elementwise ----------------
__global__ void conv_bf16_kernel(const float* __restrict__ in,
                                 u16* __restrict__ out, int n4){
    int i = blockIdx.x * 256 + threadIdx.x;
    if (i >= n4) return;
    float4v v = ((const float4v*)in)[i];
    short4v o;
    o[0] = (short)f2bf(v[0]); o[1] = (short)f2bf(v[1]);
    o[2] = (short)f2bf(v[2]); o[3] = (short)f2bf(v[3]);
    ((short4v*)out)[i] = o;
}

// ---------------- prepass: V [b][s][d] f32 -> Vt [b][d][s] bf16 ----------------
__global__ void transpose_v_kernel(const float* __restrict__ v,
                                   u16* __restrict__ vt){
    __shared__ float tile[64][65];
    const int b  = blockIdx.z;
    const int s0 = blockIdx.x << 6;
    const int d0 = blockIdx.y << 6;
    const int tx = threadIdx.x & 15;
    const int ty = threadIdx.x >> 4;
#pragma unroll
    for (int kk = 0; kk < 4; ++kk){
        const float* p = v + ((b * SS + s0 + ty + 16 * kk) * DD) + d0 + tx * 4;
        float4v val = *(const float4v*)p;
        tile[ty + 16 * kk][tx * 4 + 0] = val[0];
        tile[ty + 16 * kk][tx * 4 + 1] = val[1];
        tile[ty + 16 * kk][tx * 4 + 2] = val[2];
        tile[ty + 16 * kk][tx * 4 + 3] = val[3];
    }
    __syncthreads();
#pragma unroll
    for (int kk = 0; kk < 4; ++kk){
        int dy = ty + 16 * kk;
        short4v o;
        o[0] = (short)f2bf(tile[tx * 4 + 0][dy]);
        o[1] = (short)f2bf(tile[tx * 4 + 1][dy]);
        o[2] = (short)f2bf(tile[tx * 4 + 2][dy]);
        o[3] = (short)f2bf(tile[tx * 4 + 3][dy]);
        *(short4v*)&vt[((b * DD + d0 + dy) * SS) + s0 + tx * 4] = o;
    }
}

__global__ void zero_f32(float* __restrict__ p, int n){
    int i = blockIdx.x * 256 + threadIdx.x;
    if (i < n) p[i] = 0.f;
}

// ---------------- pass 1: S = Q K^T, mask, exp, rowsum, P bf16 ----------------
// grid (16,16,BB), 256 threads (4 waves, 2x2), 128x128 tile, BK=32.
__global__ __launch_bounds__(256, 3) void qk_kernel(
    const u16* __restrict__ Qb, const u16* __restrict__ Kb,
    const int* __restrict__ mask, u16* __restrict__ P,
    float* __restrict__ rowsum)
{
    __shared__ __align__(16) u16 Abuf[128 * 32];
    __shared__ __align__(16) u16 Bbuf[128 * 32];
    __shared__ float rsred[2][128];

    const int tid  = threadIdx.x;
    const int wid  = tid >> 6, lane = tid & 63;
    const int l16  = lane & 15, g4 = lane >> 4;
    const int wr   = wid >> 1,  wc = wid & 1;
    const int b    = blockIdx.z;
    const int row0 = blockIdx.x << 7;   // q rows
    const int col0 = blockIdx.y << 7;   // kv cols

    f32x4 acc[4][4];
    const f32x4 z4 = {0.f, 0.f, 0.f, 0.f};
#pragma unroll
    for (int i = 0; i < 4; ++i)
#pragma unroll
        for (int j = 0; j < 4; ++j) acc[i][j] = z4;

    // staging geometry: tile byte off = (c*4096) + wid*1024 + lane*16
    const int off0 = wid * 1024 + lane * 16;
    const int ar0  = off0 >> 6;          // row within 128 (c=0)
    const int ac0  = (off0 & 63) >> 1;   // bf16 col within 32

    const u16* gQ = Qb + ((size_t)(b * SS + row0 + ar0)) * DD + ac0;
    const u16* gK = Kb + ((size_t)(b * SS + col0 + ar0)) * DD + ac0;

    for (int kk = 0; kk < DD; kk += 32){
        GLD16(gQ + kk,           (char*)Abuf + wid * 1024);
        GLD16(gQ + 64 * DD + kk, (char*)Abuf + 4096 + wid * 1024);
        GLD16(gK + kk,           (char*)Bbuf + wid * 1024);
        GLD16(gK + 64 * DD + kk, (char*)Bbuf + 4096 + wid * 1024);
        __syncthreads();
        bf16x8 af[4], bfr[4];
#pragma unroll
        for (int i = 0; i < 4; ++i){
            af[i]  = *(const bf16x8*)&Abuf[(wr * 64 + i * 16 + l16) * 32 + g4 * 8];
            bfr[i] = *(const bf16x8*)&Bbuf[(wc * 64 + i * 16 + l16) * 32 + g4 * 8];
        }
#pragma unroll
        for (int i = 0; i < 4; ++i)
#pragma unroll
            for (int j = 0; j < 4; ++j)
                acc[i][j] = __builtin_amdgcn_mfma_f32_16x16x32_bf16(af[i], bfr[j], acc[i][j], 0, 0, 0);
        __syncthreads();
    }

    // epilogue: mask, exp, write P, rowsum
    float rs[4][4];
#pragma unroll
    for (int i = 0; i < 4; ++i)
#pragma unroll
        for (int r = 0; r < 4; ++r) rs[i][r] = 0.f;

#pragma unroll
    for (int i = 0; i < 4; ++i){
#pragma unroll
        for (int j = 0; j < 4; ++j){
#pragma unroll
            for (int r = 0; r < 4; ++r){
                const int grow = row0 + wr * 64 + i * 16 + g4 * 4 + r;
                const int gcol = col0 + wc * 64 + j * 16 + l16;
                const size_t idx = ((size_t)(b * SS + grow)) * SS + gcol;
                int m = mask[idx];
                float e = m ? __expf(acc[i][j][r] * SCALE) : 0.f;
                P[idx] = f2bf(e);
                rs[i][r] += e;
            }
        }
    }
#pragma unroll
    for (int i = 0; i < 4; ++i)
#pragma unroll
        for (int r = 0; r < 4; ++r){
            float v = rs[i][r];
            v += __shfl_xor(v, 1); v += __shfl_xor(v, 2);
            v += __shfl_xor(v, 4); v += __shfl_xor(v, 8);
            if (l16 == 0) rsred[wc][wr * 64 + i * 16 + g4 * 4 + r] = v;
        }
    __syncthreads();
    if (tid < 128)
        atomicAdd(&rowsum[b * SS + row0 + tid], rsred[0][tid] + rsred[1][tid]);
}

// ---------------- pass 2: X = (P V) / rowsum, bf16 ----------------
// grid (16,8,BB): x -> q rows, y -> d cols. K = SS = 2048.
__global__ __launch_bounds__(256, 3) void pv_kernel(
    const u16* __restrict__ P, const u16* __restrict__ Vt,
    const float* __restrict__ rowsum, u16* __restrict__ Xn)
{
    __shared__ __align__(16) u16 Abuf[128 * 32];
    __shared__ __align__(16) u16 Bbuf[128 * 32];

    const int tid  = threadIdx.x;
    const int wid  = tid >> 6, lane = tid & 63;
    const int l16  = lane & 15, g4 = lane >> 4;
    const int wr   = wid >> 1,  wc = wid & 1;
    const int b    = blockIdx.z;
    const int row0 = blockIdx.x << 7;   // q rows
    const int col0 = blockIdx.y << 7;   // d cols

    f32x4 acc[4][4];
    const f32x4 z4 = {0.f, 0.f, 0.f, 0.f};
#pragma unroll
    for (int i = 0; i < 4; ++i)
#pragma unroll
        for (int j = 0; j < 4; ++j) acc[i][j] = z4;

    const int off0 = wid * 1024 + lane * 16;
    const int ar0  = off0 >> 6;
    const int ac0  = (off0 & 63) >> 1;

    const u16* gP = P  + ((size_t)(b * SS + row0 + ar0)) * SS + ac0;
    const u16* gV = Vt + ((size_t)(b * DD + col0 + ar0)) * SS + ac0;

    for (int kk = 0; kk < SS; kk += 32){
        GLD16(gP + kk,           (char*)Abuf + wid * 1024);
        GLD16(gP + 64 * SS + kk, (char*)Abuf + 4096 + wid * 1024);
        GLD16(gV + kk,           (char*)Bbuf + wid * 1024);
        GLD16(gV + 64 * SS + kk, (char*)Bbuf + 4096 + wid * 1024);
        __syncthreads();
        bf16x8 af[4], bfr[4];
#pragma unroll
        for (int i = 0; i < 4; ++i){
            af[i]  = *(const bf16x8*)&Abuf[(wr * 64 + i * 16 + l16) * 32 + g4 * 8];
            bfr[i] = *(const bf16x8*)&Bbuf[(wc * 64 + i * 16 + l16) * 32 + g4 * 8];
        }
#pragma unroll
        for (int i = 0; i < 4; ++i)
#pragma unroll
            for (int j = 0; j < 4; ++j)
                acc[i][j] = __builtin_amdgcn_mfma_f32_16x16x32_bf16(af[i], bfr[j], acc[i][j], 0, 0, 0);
        __syncthreads();
    }

#pragma unroll
    for (int i = 0; i < 4; ++i){
        float inv[4];
#pragma unroll
        for (int r = 0; r < 4; ++r)
            inv[r] = 1.f / rowsum[b * SS + row0 + wr * 64 + i * 16 + g4 * 4 + r];
#pragma unroll
        for (int j = 0; j < 4; ++j){
#pragma unroll
            for (int r = 0; r < 4; ++r){
                const int grow = row0 + wr * 64 + i * 16 + g4 * 4 + r;
                const int gcol = col0 + wc * 64 + j * 16 + l16;
                Xn[((size_t)(b * SS + grow)) * DD + gcol] = f2bf(acc[i][j][r] * inv[r]);
            }
        }
    }
}

// ---------------- pass 3: LayerNorm over d ----------------
__global__ __launch_bounds__(256) void ln_kernel(
    const u16* __restrict__ Xn, const float* __restrict__ gamma,
    const float* __restrict__ beta, float* __restrict__ out)
{
    __shared__ float red[2][4];
    const int row = blockIdx.x;      // b*S + s
    const int t = threadIdx.x;
    short4v xv = *(const short4v*)&Xn[(size_t)row * DD + t * 4];
    float x[4];
#pragma unroll
    for (int j = 0; j < 4; ++j)
        x[j] = __uint_as_float(((unsigned)(u16)xv[j]) << 16);
    float s  = x[0] + x[1] + x[2] + x[3];
    float sq = x[0]*x[0] + x[1]*x[1] + x[2]*x[2] + x[3]*x[3];
#pragma unroll
    for (int d = 1; d < 64; d <<= 1){ s += __shfl_xor(s, d); sq += __shfl_xor(sq, d); }
    const int wv = t >> 6;
    if ((t & 63) == 0){ red[0][wv] = s; red[1][wv] = sq; }
    __syncthreads();
    float S  = red[0][0] + red[0][1] + red[0][2] + red[0][3];
    float Sq = red[1][0] + red[1][1] + red[1][2] + red[1][3];
    float mu = S * (1.f / 1024.f);
    float var = Sq * (1.f / 1024.f) - mu * mu;
    float rstd = rsqrtf(var + 1e-5f);
    float4v g  = *(const float4v*)&gamma[t * 4];
    float4v be = *(const float4v*)&beta[t * 4];
    float4v o;
#pragma unroll
    for (int j = 0; j < 4; ++j) o[j] = (x[j] - mu) * rstd * g[j] + be[j];
    *(float4v*)&out[(size_t)row * DD + t * 4] = o;
}

extern "C" void kernel_launch(void* const* d_in, const int* in_sizes, int n_in,
                              void* d_out, int out_size, void* d_ws, size_t ws_size,
                              hipStream_t stream) {
    const float* q     = (const float*)d_in[0];
    const float* k     = (const float*)d_in[1];
    const float* v     = (const float*)d_in[2];
    const int*   mask  = (const int*)d_in[3];
    const float* gamma = (const float*)d_in[4];
    const float* beta  = (const float*)d_in[5];
    float* out = (float*)d_out;

    u16* Qb = (u16*)d_ws;                                  // 16 MB
    u16* Kb = Qb + (size_t)BB * SS * DD;                   // 16 MB
    u16* Vt = Kb + (size_t)BB * SS * DD;                   // 16 MB
    u16* P  = Vt + (size_t)BB * SS * DD;                   // 32 MB
    u16* Xn = P  + (size_t)BB * SS * SS;                   // 16 MB
    float* rowsum = (float*)(Xn + (size_t)BB * SS * DD);   // 32 KB

    const int n4 = BB * SS * DD / 4;
    conv_bf16_kernel<<<n4 / 256, 256, 0, stream>>>(q, Qb, n4);
    conv_bf16_kernel<<<n4 / 256, 256, 0, stream>>>(k, Kb, n4);
    transpose_v_kernel<<<dim3(SS / 64, DD / 64, BB), 256, 0, stream>>>(v, Vt);
    zero_f32<<<BB * SS / 256, 256, 0, stream>>>(rowsum, BB * SS);

    qk_kernel<<<dim3(16, 16, BB), 256, 0, stream>>>(Qb, Kb, mask, P, rowsum);
    pv_kernel<<<dim3(16, 8, BB), 256, 0, stream>>>(P, Vt, rowsum, Xn);
    ln_kernel<<<BB * SS, 256, 0, stream>>>(Xn, gamma, beta, out);
}

// Round 3
// 162.677 us; speedup vs baseline: 3.0744x; 1.0016x over previous
//
#include <hip/hip_runtime.h>
#include <hip/hip_bf16.h>

typedef unsigned short u16;
typedef __attribute__((ext_vector_type(8))) short bf16x8;
typedef __attribute__((ext_vector_type(4))) float f32x4;
typedef __attribute__((ext_vector_type(4))) float float4v;
typedef __attribute__((ext_vector_type(4))) short short4v;

#define BB 4
#define SS 2048
#define DD 1024

__device__ __forceinline__ u16 f2bf(float x){
    unsigned u = __float_as_uint(x);
    return (u16)((u + 0x7fffu + ((u >> 16) & 1u)) >> 16);  // RNE
}

#define GLD16(g, l) __builtin_amdgcn_global_load_lds( \
    (const __attribute__((address_space(1))) unsigned int*)(g), \
    (__attribute__((address_space(3))) unsigned int*)(l), 16, 0, 0)

// ---------------- prepass: f32 -> bf16 elementwise (optional scale) ----------------
__global__ void conv_bf16_kernel(const float* __restrict__ in,
                                 u16* __restrict__ out, int n4, float scale){
    int i = blockIdx.x * 256 + threadIdx.x;
    if (i >= n4) return;
    float4v v = ((const float4v*)in)[i];
    short4v o;
    o[0] = (short)f2bf(v[0] * scale); o[1] = (short)f2bf(v[1] * scale);
    o[2] = (short)f2bf(v[2] * scale); o[3] = (short)f2bf(v[3] * scale);
    ((short4v*)out)[i] = o;
}

// ---------------- prepass: V [b][s][d] f32 -> Vt [b][d][s] bf16 ----------------
__global__ void transpose_v_kernel(const float* __restrict__ v,
                                   u16* __restrict__ vt){
    __shared__ float tile[64][65];
    const int b  = blockIdx.z;
    const int s0 = blockIdx.x << 6;
    const int d0 = blockIdx.y << 6;
    const int tx = threadIdx.x & 15;
    const int ty = threadIdx.x >> 4;
#pragma unroll
    for (int kk = 0; kk < 4; ++kk){
        const float* p = v + ((b * SS + s0 + ty + 16 * kk) * DD) + d0 + tx * 4;
        float4v val = *(const float4v*)p;
        tile[ty + 16 * kk][tx * 4 + 0] = val[0];
        tile[ty + 16 * kk][tx * 4 + 1] = val[1];
        tile[ty + 16 * kk][tx * 4 + 2] = val[2];
        tile[ty + 16 * kk][tx * 4 + 3] = val[3];
    }
    __syncthreads();
#pragma unroll
    for (int kk = 0; kk < 4; ++kk){
        int dy = ty + 16 * kk;
        short4v o;
        o[0] = (short)f2bf(tile[tx * 4 + 0][dy]);
        o[1] = (short)f2bf(tile[tx * 4 + 1][dy]);
        o[2] = (short)f2bf(tile[tx * 4 + 2][dy]);
        o[3] = (short)f2bf(tile[tx * 4 + 3][dy]);
        *(short4v*)&vt[((b * DD + d0 + dy) * SS) + s0 + tx * 4] = o;
    }
}

__global__ void zero_f32(float* __restrict__ p, int n){
    int i = blockIdx.x * 256 + threadIdx.x;
    if (i < n) p[i] = 0.f;
}

// ---------------- pass 1: S = Qs K^T, mask, exp, rowsum, P bf16 ----------------
// 1D grid 1024 blocks (XCD-swizzled), 256 threads (4 waves 2x2), 128x128 tile, BK=32.
// T3-min: dbuf LDS, stage(t+1) issued BEFORE compute(t), ONE barrier per K-step.
__global__ __launch_bounds__(256, 4) void qk_kernel(
    const u16* __restrict__ Qb, const u16* __restrict__ Kb,
    const int* __restrict__ mask, u16* __restrict__ P,
    float* __restrict__ rowsum)
{
    __shared__ __align__(16) u16 Abuf[2][128 * 32];
    __shared__ __align__(16) u16 Bbuf[2][128 * 32];
    __shared__ float rsred[2][128];

    // XCD-aware swizzle of flat block id (1024 % 8 == 0 -> bijective)
    const int flat = blockIdx.x;
    const int swz  = (flat & 7) * 128 + (flat >> 3);
    const int bx = swz & 15, by = (swz >> 4) & 15, b = swz >> 8;

    const int tid  = threadIdx.x;
    const int wid  = tid >> 6, lane = tid & 63;
    const int l16  = lane & 15, g4 = lane >> 4;
    const int wr   = wid >> 1,  wc = wid & 1;
    const int row0 = bx << 7;   // q rows
    const int col0 = by << 7;   // kv cols

    f32x4 acc[4][4];
    const f32x4 z4 = {0.f, 0.f, 0.f, 0.f};
#pragma unroll
    for (int i = 0; i < 4; ++i)
#pragma unroll
        for (int j = 0; j < 4; ++j) acc[i][j] = z4;

    // staging geometry: per matrix 2 GLD16/thread, sweep = 64 rows
    const int off0 = wid * 1024 + lane * 16;      // [0,4096) bytes
    const int ar0  = off0 >> 6;                   // row (64B rows at BK=32)
    const int ac0  = (off0 & 63) >> 1;            // bf16 col
    const int ldso = wid * 1024 + lane * 16;

    const u16* gQ = Qb + ((size_t)(b * SS + row0 + ar0)) * DD + ac0;
    const u16* gK = Kb + ((size_t)(b * SS + col0 + ar0)) * DD + ac0;

#define QK_STAGE(t, bi) { \
    GLD16(gQ + (t) * 32,            (char*)Abuf[bi] + ldso); \
    GLD16(gQ + 64 * DD + (t) * 32,  (char*)Abuf[bi] + 4096 + ldso); \
    GLD16(gK + (t) * 32,            (char*)Bbuf[bi] + ldso); \
    GLD16(gK + 64 * DD + (t) * 32,  (char*)Bbuf[bi] + 4096 + ldso); }

    QK_STAGE(0, 0);
    __syncthreads();

    const int NT = DD / 32;   // 32
    for (int t = 0; t < NT; ++t){
        const int cur = t & 1;
        if (t + 1 < NT) QK_STAGE(t + 1, cur ^ 1);
        bf16x8 af[4], bfr[4];
#pragma unroll
        for (int i = 0; i < 4; ++i){
            af[i]  = *(const bf16x8*)&Abuf[cur][(wr * 64 + i * 16 + l16) * 32 + g4 * 8];
            bfr[i] = *(const bf16x8*)&Bbuf[cur][(wc * 64 + i * 16 + l16) * 32 + g4 * 8];
        }
#pragma unroll
        for (int i = 0; i < 4; ++i)
#pragma unroll
            for (int j = 0; j < 4; ++j)
                acc[i][j] = __builtin_amdgcn_mfma_f32_16x16x32_bf16(af[i], bfr[j], acc[i][j], 0, 0, 0);
        __syncthreads();
    }
#undef QK_STAGE

    // epilogue: mask, exp (scale pre-folded into Qb), write P, rowsum
    float rs[4][4];
#pragma unroll
    for (int i = 0; i < 4; ++i)
#pragma unroll
        for (int r = 0; r < 4; ++r) rs[i][r] = 0.f;

#pragma unroll
    for (int i = 0; i < 4; ++i){
#pragma unroll
        for (int j = 0; j < 4; ++j){
#pragma unroll
            for (int r = 0; r < 4; ++r){
                const int grow = row0 + wr * 64 + i * 16 + g4 * 4 + r;
                const int gcol = col0 + wc * 64 + j * 16 + l16;
                const size_t idx = ((size_t)(b * SS + grow)) * SS + gcol;
                int m = mask[idx];
                float e = m ? __expf(acc[i][j][r]) : 0.f;
                P[idx] = f2bf(e);
                rs[i][r] += e;
            }
        }
    }
#pragma unroll
    for (int i = 0; i < 4; ++i)
#pragma unroll
        for (int r = 0; r < 4; ++r){
            float v = rs[i][r];
            v += __shfl_xor(v, 1); v += __shfl_xor(v, 2);
            v += __shfl_xor(v, 4); v += __shfl_xor(v, 8);
            if (l16 == 0) rsred[wc][wr * 64 + i * 16 + g4 * 4 + r] = v;
        }
    __syncthreads();
    if (tid < 128)
        atomicAdd(&rowsum[b * SS + row0 + tid], rsred[0][tid] + rsred[1][tid]);
}

// ---------------- pass 2: X = (P V) / rowsum, bf16 ----------------
// 1D grid 512 blocks (XCD-swizzled): 16 row-tiles x 8 col-tiles x B. K = 2048.
__global__ __launch_bounds__(256, 4) void pv_kernel(
    const u16* __restrict__ P, const u16* __restrict__ Vt,
    const float* __restrict__ rowsum, u16* __restrict__ Xn)
{
    __shared__ __align__(16) u16 Abuf[2][128 * 32];
    __shared__ __align__(16) u16 Bbuf[2][128 * 32];

    const int flat = blockIdx.x;
    const int swz  = (flat & 7) * 64 + (flat >> 3);
    const int bx = swz & 15, by = (swz >> 4) & 7, b = swz >> 7;

    const int tid  = threadIdx.x;
    const int wid  = tid >> 6, lane = tid & 63;
    const int l16  = lane & 15, g4 = lane >> 4;
    const int wr   = wid >> 1,  wc = wid & 1;
    const int row0 = bx << 7;   // q rows
    const int col0 = by << 7;   // d cols

    f32x4 acc[4][4];
    const f32x4 z4 = {0.f, 0.f, 0.f, 0.f};
#pragma unroll
    for (int i = 0; i < 4; ++i)
#pragma unroll
        for (int j = 0; j < 4; ++j) acc[i][j] = z4;

    const int off0 = wid * 1024 + lane * 16;
    const int ar0  = off0 >> 6;
    const int ac0  = (off0 & 63) >> 1;
    const int ldso = wid * 1024 + lane * 16;

    const u16* gP = P  + ((size_t)(b * SS + row0 + ar0)) * SS + ac0;
    const u16* gV = Vt + ((size_t)(b * DD + col0 + ar0)) * SS + ac0;

#define PV_STAGE(t, bi) { \
    GLD16(gP + (t) * 32,            (char*)Abuf[bi] + ldso); \
    GLD16(gP + 64 * SS + (t) * 32,  (char*)Abuf[bi] + 4096 + ldso); \
    GLD16(gV + (t) * 32,            (char*)Bbuf[bi] + ldso); \
    GLD16(gV + 64 * SS + (t) * 32,  (char*)Bbuf[bi] + 4096 + ldso); }

    PV_STAGE(0, 0);
    __syncthreads();

    const int NT = SS / 32;   // 64
    for (int t = 0; t < NT; ++t){
        const int cur = t & 1;
        if (t + 1 < NT) PV_STAGE(t + 1, cur ^ 1);
        bf16x8 af[4], bfr[4];
#pragma unroll
        for (int i = 0; i < 4; ++i){
            af[i]  = *(const bf16x8*)&Abuf[cur][(wr * 64 + i * 16 + l16) * 32 + g4 * 8];
            bfr[i] = *(const bf16x8*)&Bbuf[cur][(wc * 64 + i * 16 + l16) * 32 + g4 * 8];
        }
#pragma unroll
        for (int i = 0; i < 4; ++i)
#pragma unroll
            for (int j = 0; j < 4; ++j)
                acc[i][j] = __builtin_amdgcn_mfma_f32_16x16x32_bf16(af[i], bfr[j], acc[i][j], 0, 0, 0);
        __syncthreads();
    }
#undef PV_STAGE

#pragma unroll
    for (int i = 0; i < 4; ++i){
        float inv[4];
#pragma unroll
        for (int r = 0; r < 4; ++r)
            inv[r] = 1.f / rowsum[b * SS + row0 + wr * 64 + i * 16 + g4 * 4 + r];
#pragma unroll
        for (int j = 0; j < 4; ++j){
#pragma unroll
            for (int r = 0; r < 4; ++r){
                const int grow = row0 + wr * 64 + i * 16 + g4 * 4 + r;
                const int gcol = col0 + wc * 64 + j * 16 + l16;
                Xn[((size_t)(b * SS + grow)) * DD + gcol] = f2bf(acc[i][j][r] * inv[r]);
            }
        }
    }
}

// ---------------- pass 3: LayerNorm over d ----------------
__global__ __launch_bounds__(256) void ln_kernel(
    const u16* __restrict__ Xn, const float* __restrict__ gamma,
    const float* __restrict__ beta, float* __restrict__ out)
{
    __shared__ float red[2][4];
    const int row = blockIdx.x;      // b*S + s
    const int t = threadIdx.x;
    short4v xv = *(const short4v*)&Xn[(size_t)row * DD + t * 4];
    float x[4];
#pragma unroll
    for (int j = 0; j < 4; ++j)
        x[j] = __uint_as_float(((unsigned)(u16)xv[j]) << 16);
    float s  = x[0] + x[1] + x[2] + x[3];
    float sq = x[0]*x[0] + x[1]*x[1] + x[2]*x[2] + x[3]*x[3];
#pragma unroll
    for (int d = 1; d < 64; d <<= 1){ s += __shfl_xor(s, d); sq += __shfl_xor(sq, d); }
    const int wv = t >> 6;
    if ((t & 63) == 0){ red[0][wv] = s; red[1][wv] = sq; }
    __syncthreads();
    float S  = red[0][0] + red[0][1] + red[0][2] + red[0][3];
    float Sq = red[1][0] + red[1][1] + red[1][2] + red[1][3];
    float mu = S * (1.f / 1024.f);
    float var = Sq * (1.f / 1024.f) - mu * mu;
    float rstd = rsqrtf(var + 1e-5f);
    float4v g  = *(const float4v*)&gamma[t * 4];
    float4v be = *(const float4v*)&beta[t * 4];
    float4v o;
#pragma unroll
    for (int j = 0; j < 4; ++j) o[j] = (x[j] - mu) * rstd * g[j] + be[j];
    *(float4v*)&out[(size_t)row * DD + t * 4] = o;
}

extern "C" void kernel_launch(void* const* d_in, const int* in_sizes, int n_in,
                              void* d_out, int out_size, void* d_ws, size_t ws_size,
                              hipStream_t stream) {
    const float* q     = (const float*)d_in[0];
    const float* k     = (const float*)d_in[1];
    const float* v     = (const float*)d_in[2];
    const int*   mask  = (const int*)d_in[3];
    const float* gamma = (const float*)d_in[4];
    const float* beta  = (const float*)d_in[5];
    float* out = (float*)d_out;

    u16* Qb = (u16*)d_ws;                                  // 16 MB  (pre-scaled by 1/sqrt(d))
    u16* Kb = Qb + (size_t)BB * SS * DD;                   // 16 MB
    u16* Vt = Kb + (size_t)BB * SS * DD;                   // 16 MB
    u16* P  = Vt + (size_t)BB * SS * DD;                   // 32 MB
    u16* Xn = P  + (size_t)BB * SS * SS;                   // 16 MB
    float* rowsum = (float*)(Xn + (size_t)BB * SS * DD);   // 32 KB

    const int n4 = BB * SS * DD / 4;
    conv_bf16_kernel<<<n4 / 256, 256, 0, stream>>>(q, Qb, n4, 0.03125f);
    conv_bf16_kernel<<<n4 / 256, 256, 0, stream>>>(k, Kb, n4, 1.0f);
    transpose_v_kernel<<<dim3(SS / 64, DD / 64, BB), 256, 0, stream>>>(v, Vt);
    zero_f32<<<BB * SS / 256, 256, 0, stream>>>(rowsum, BB * SS);

    qk_kernel<<<BB * 16 * 16, 256, 0, stream>>>(Qb, Kb, mask, P, rowsum);
    pv_kernel<<<BB * 16 * 8, 256, 0, stream>>>(P, Vt, rowsum, Xn);
    ln_kernel<<<BB * SS, 256, 0, stream>>>(Xn, gamma, beta, out);
}

// Round 4
// 145.058 us; speedup vs baseline: 3.4479x; 1.1215x over previous
//
#include <hip/hip_runtime.h>
#include <hip/hip_bf16.h>

typedef unsigned short u16;
typedef __attribute__((ext_vector_type(8))) short bf16x8;
typedef __attribute__((ext_vector_type(4))) float f32x4;
typedef __attribute__((ext_vector_type(4))) float float4v;
typedef __attribute__((ext_vector_type(4))) short short4v;

#define BB 4
#define SS 2048
#define DD 1024

__device__ __forceinline__ u16 f2bf(float x){
    unsigned u = __float_as_uint(x);
    return (u16)((u + 0x7fffu + ((u >> 16) & 1u)) >> 16);  // RNE
}

#define GLD16(g, l) __builtin_amdgcn_global_load_lds( \
    (const __attribute__((address_space(1))) unsigned int*)(g), \
    (__attribute__((address_space(3))) unsigned int*)(l), 16, 0, 0)

#define SCHED0() __builtin_amdgcn_sched_barrier(0)
#define PH_PRE()  SCHED0(); __builtin_amdgcn_s_barrier(); SCHED0(); __builtin_amdgcn_s_setprio(1)
#define PH_POST() __builtin_amdgcn_s_setprio(0); SCHED0(); __builtin_amdgcn_s_barrier(); SCHED0()

// ---------------- prepass: f32 -> bf16 elementwise (optional scale) ----------------
__global__ void conv_bf16_kernel(const float* __restrict__ in,
                                 u16* __restrict__ out, int n4, float scale){
    int i = blockIdx.x * 256 + threadIdx.x;
    if (i >= n4) return;
    float4v v = ((const float4v*)in)[i];
    short4v o;
    o[0] = (short)f2bf(v[0] * scale); o[1] = (short)f2bf(v[1] * scale);
    o[2] = (short)f2bf(v[2] * scale); o[3] = (short)f2bf(v[3] * scale);
    ((short4v*)out)[i] = o;
}

// ---------------- prepass: V [b][s][d] f32 -> Vt [b][d][s] bf16 ----------------
__global__ void transpose_v_kernel(const float* __restrict__ v,
                                   u16* __restrict__ vt){
    __shared__ float tile[64][65];
    const int b  = blockIdx.z;
    const int s0 = blockIdx.x << 6;
    const int d0 = blockIdx.y << 6;
    const int tx = threadIdx.x & 15;
    const int ty = threadIdx.x >> 4;
#pragma unroll
    for (int kk = 0; kk < 4; ++kk){
        const float* p = v + ((b * SS + s0 + ty + 16 * kk) * DD) + d0 + tx * 4;
        float4v val = *(const float4v*)p;
        tile[ty + 16 * kk][tx * 4 + 0] = val[0];
        tile[ty + 16 * kk][tx * 4 + 1] = val[1];
        tile[ty + 16 * kk][tx * 4 + 2] = val[2];
        tile[ty + 16 * kk][tx * 4 + 3] = val[3];
    }
    __syncthreads();
#pragma unroll
    for (int kk = 0; kk < 4; ++kk){
        int dy = ty + 16 * kk;
        short4v o;
        o[0] = (short)f2bf(tile[tx * 4 + 0][dy]);
        o[1] = (short)f2bf(tile[tx * 4 + 1][dy]);
        o[2] = (short)f2bf(tile[tx * 4 + 2][dy]);
        o[3] = (short)f2bf(tile[tx * 4 + 3][dy]);
        *(short4v*)&vt[((b * DD + d0 + dy) * SS) + s0 + tx * 4] = o;
    }
}

__global__ void zero_f32(float* __restrict__ p, int n){
    int i = blockIdx.x * 256 + threadIdx.x;
    if (i < n) p[i] = 0.f;
}

// ---------------- pass 1: S = Qs K^T -> exp/mask -> P bf16, rowsum ----------------
// 256 blocks, 512 threads (8 waves 2x4). 256x256 tile, BK=64, 8-phase counted-vmcnt.
// LDS swizzle: col_byte ^= ((row&7)<<4), applied on global source AND ds_read.
__global__ __launch_bounds__(512, 2) void qk_kernel(
    const u16* __restrict__ Qb, const u16* __restrict__ Kb,
    const int* __restrict__ mask, u16* __restrict__ P,
    float* __restrict__ rowsum)
{
    __shared__ __align__(16) u16 As[2][256 * 64];   // 64 KB
    __shared__ __align__(16) u16 Bs[2][256 * 64];   // 64 KB

    const int swz = ((blockIdx.x & 7) << 5) + (blockIdx.x >> 3);  // 256 blocks, bijective
    const int b   = swz >> 6;
    const int bx  = (swz >> 3) & 7;
    const int by  = swz & 7;
    const int row0 = bx << 8, col0 = by << 8;

    const int tid = threadIdx.x;
    const int wid = tid >> 6, lane = tid & 63;
    const int l16 = lane & 15, g4 = lane >> 4;
    const int wr = wid >> 2, wc = wid & 3;

    // staging: thread covers rows sr + j*64, 16B at swizzled col
    const int sr   = tid >> 3;
    const int scol = ((tid & 7) ^ (sr & 7)) << 3;       // element col (pre-swizzled source)
    const u16* gA = Qb + (size_t)(b * SS + row0 + sr) * DD + scol;
    const u16* gB = Kb + (size_t)(b * SS + col0 + sr) * DD + scol;
    char* const lA0 = (char*)As[0] + tid * 16;
    char* const lB0 = (char*)Bs[0] + tid * 16;
    char* const lA1 = (char*)As[1] + tid * 16;
    char* const lB1 = (char*)Bs[1] + tid * 16;

    // ds_read geometry (bytes): row*128 + (col ^ ((row&7)<<4))
    const int aRow = (wr * 128 + l16) << 7;
    const int bRow = (wc * 64  + l16) << 7;
    const int cx0  = (g4 << 4) ^ ((l16 & 7) << 4);      // kh=1 -> cx0 ^ 64

    f32x4 acc[8][4];
    const f32x4 z4 = {0.f, 0.f, 0.f, 0.f};
#pragma unroll
    for (int i = 0; i < 8; ++i)
#pragma unroll
        for (int j = 0; j < 4; ++j) acc[i][j] = z4;

#define STAGE_QK(kt, la, lb) { \
    const u16* ga_ = gA + (kt) * 64; \
    const u16* gb_ = gB + (kt) * 64; \
    GLD16(ga_,            (la)); \
    GLD16(ga_ +  64 * DD, (la) + 8192); \
    GLD16(ga_ + 128 * DD, (la) + 16384); \
    GLD16(ga_ + 192 * DD, (la) + 24576); \
    GLD16(gb_,            (lb)); \
    GLD16(gb_ +  64 * DD, (lb) + 8192); \
    GLD16(gb_ + 128 * DD, (lb) + 16384); \
    GLD16(gb_ + 192 * DD, (lb) + 24576); }

#define LDA4(Ab_, mh, kx) { \
    const char* p_ = (const char*)(Ab_) + aRow + (mh) * 8192 + ((kx) ? (cx0 ^ 64) : cx0); \
    fa0 = *(const bf16x8*)(p_); \
    fa1 = *(const bf16x8*)(p_ + 2048); \
    fa2 = *(const bf16x8*)(p_ + 4096); \
    fa3 = *(const bf16x8*)(p_ + 6144); }

#define LDB4(Bb_, kx) { \
    const char* p_ = (const char*)(Bb_) + bRow + ((kx) ? (cx0 ^ 64) : cx0); \
    fb0 = *(const bf16x8*)(p_); \
    fb1 = *(const bf16x8*)(p_ + 2048); \
    fb2 = *(const bf16x8*)(p_ + 4096); \
    fb3 = *(const bf16x8*)(p_ + 6144); }

#define MROWQ(mi, fa) \
    acc[mi][0] = __builtin_amdgcn_mfma_f32_16x16x32_bf16(fa, fb0, acc[mi][0],0,0,0); \
    acc[mi][1] = __builtin_amdgcn_mfma_f32_16x16x32_bf16(fa, fb1, acc[mi][1],0,0,0); \
    acc[mi][2] = __builtin_amdgcn_mfma_f32_16x16x32_bf16(fa, fb2, acc[mi][2],0,0,0); \
    acc[mi][3] = __builtin_amdgcn_mfma_f32_16x16x32_bf16(fa, fb3, acc[mi][3],0,0,0);

    // prologue: K-tiles 0,1
    STAGE_QK(0, lA0, lB0);
    STAGE_QK(1, lA1, lB1);
    asm volatile("s_waitcnt vmcnt(8)" ::: "memory");
    SCHED0(); __builtin_amdgcn_s_barrier(); SCHED0();

#pragma unroll 1
    for (int it = 0; it < 8; ++it){
        bf16x8 fa0, fa1, fa2, fa3, fb0, fb1, fb2, fb3;
        // ---- K-tile 2it from buf0 (phases 0-3) ----
        LDA4(As[0], 0, 0); LDB4(Bs[0], 0);
        PH_PRE(); MROWQ(0,fa0) MROWQ(1,fa1) MROWQ(2,fa2) MROWQ(3,fa3) PH_POST();
        LDA4(As[0], 1, 0);
        PH_PRE(); MROWQ(4,fa0) MROWQ(5,fa1) MROWQ(6,fa2) MROWQ(7,fa3) PH_POST();
        LDA4(As[0], 0, 1); LDB4(Bs[0], 1);
        PH_PRE(); MROWQ(0,fa0) MROWQ(1,fa1) MROWQ(2,fa2) MROWQ(3,fa3) PH_POST();
        LDA4(As[0], 1, 1);
        PH_PRE(); MROWQ(4,fa0) MROWQ(5,fa1) MROWQ(6,fa2) MROWQ(7,fa3) PH_POST();
        // ---- mid boundary: buf0 fully consumed -> stage K-tile 2it+2 into it ----
        if (it < 7){
            STAGE_QK(2*it+2, lA0, lB0);
            asm volatile("s_waitcnt vmcnt(8)" ::: "memory");   // buf1's loads done
        } else {
            asm volatile("s_waitcnt vmcnt(0)" ::: "memory");
        }
        SCHED0(); __builtin_amdgcn_s_barrier(); SCHED0();
        // ---- K-tile 2it+1 from buf1 (phases 4-7) ----
        LDA4(As[1], 0, 0); LDB4(Bs[1], 0);
        PH_PRE(); MROWQ(0,fa0) MROWQ(1,fa1) MROWQ(2,fa2) MROWQ(3,fa3) PH_POST();
        LDA4(As[1], 1, 0);
        PH_PRE(); MROWQ(4,fa0) MROWQ(5,fa1) MROWQ(6,fa2) MROWQ(7,fa3) PH_POST();
        LDA4(As[1], 0, 1); LDB4(Bs[1], 1);
        PH_PRE(); MROWQ(0,fa0) MROWQ(1,fa1) MROWQ(2,fa2) MROWQ(3,fa3) PH_POST();
        LDA4(As[1], 1, 1);
        PH_PRE(); MROWQ(4,fa0) MROWQ(5,fa1) MROWQ(6,fa2) MROWQ(7,fa3) PH_POST();
        // ---- end boundary: buf1 consumed -> stage K-tile 2it+3 ----
        if (it < 7){
            STAGE_QK(2*it+3, lA1, lB1);
            asm volatile("s_waitcnt vmcnt(8)" ::: "memory");   // buf0's loads done
            SCHED0(); __builtin_amdgcn_s_barrier(); SCHED0();
        }
    }
#undef STAGE_QK
#undef LDA4
#undef LDB4
#undef MROWQ

    // epilogue: mask, exp (scale pre-folded into Qb), write P, rowsum atomics
#pragma unroll
    for (int m = 0; m < 8; ++m){
        float rsum[4] = {0.f, 0.f, 0.f, 0.f};
#pragma unroll
        for (int n = 0; n < 4; ++n){
            const int gcol = col0 + wc * 64 + n * 16 + l16;
#pragma unroll
            for (int r = 0; r < 4; ++r){
                const int grow = row0 + wr * 128 + m * 16 + g4 * 4 + r;
                const size_t idx = (size_t)(b * SS + grow) * SS + gcol;
                float e = mask[idx] ? __expf(acc[m][n][r]) : 0.f;
                P[idx] = f2bf(e);
                rsum[r] += e;
            }
        }
#pragma unroll
        for (int r = 0; r < 4; ++r){
            float v2 = rsum[r];
            v2 += __shfl_xor(v2, 1); v2 += __shfl_xor(v2, 2);
            v2 += __shfl_xor(v2, 4); v2 += __shfl_xor(v2, 8);
            if (l16 == 0)
                atomicAdd(&rowsum[b * SS + row0 + wr * 128 + m * 16 + g4 * 4 + r], v2);
        }
    }
}

// ---------------- pass 2: X = (P V) / rowsum -> bf16 ----------------
// 256 blocks, 512 threads. 128x256 tile, BK=64, same 8-phase schedule (8 MFMA/phase).
__global__ __launch_bounds__(512, 2) void pv_kernel(
    const u16* __restrict__ P, const u16* __restrict__ Vt,
    const float* __restrict__ rowsum, u16* __restrict__ Xn)
{
    __shared__ __align__(16) u16 As[2][128 * 64];   // 32 KB
    __shared__ __align__(16) u16 Bs[2][256 * 64];   // 64 KB

    const int swz = ((blockIdx.x & 7) << 5) + (blockIdx.x >> 3);
    const int b   = swz >> 6;
    const int bx  = (swz >> 2) & 15;
    const int by  = swz & 3;
    const int row0 = bx << 7, col0 = by << 8;

    const int tid = threadIdx.x;
    const int wid = tid >> 6, lane = tid & 63;
    const int l16 = lane & 15, g4 = lane >> 4;
    const int wr = wid >> 2, wc = wid & 3;

    const int sr   = tid >> 3;
    const int scol = ((tid & 7) ^ (sr & 7)) << 3;
    const u16* gA = P  + (size_t)(b * SS + row0 + sr) * SS + scol;
    const u16* gB = Vt + (size_t)(b * DD + col0 + sr) * SS + scol;
    char* const lA0 = (char*)As[0] + tid * 16;
    char* const lB0 = (char*)Bs[0] + tid * 16;
    char* const lA1 = (char*)As[1] + tid * 16;
    char* const lB1 = (char*)Bs[1] + tid * 16;

    const int aRow = (wr * 64 + l16) << 7;
    const int bRow = (wc * 64 + l16) << 7;
    const int cx0  = (g4 << 4) ^ ((l16 & 7) << 4);

    f32x4 acc[4][4];
    const f32x4 z4 = {0.f, 0.f, 0.f, 0.f};
#pragma unroll
    for (int i = 0; i < 4; ++i)
#pragma unroll
        for (int j = 0; j < 4; ++j) acc[i][j] = z4;

#define STAGE_PV(kt, la, lb) { \
    const u16* ga_ = gA + (kt) * 64; \
    const u16* gb_ = gB + (kt) * 64; \
    GLD16(ga_,            (la)); \
    GLD16(ga_ +  64 * SS, (la) + 8192); \
    GLD16(gb_,            (lb)); \
    GLD16(gb_ +  64 * SS, (lb) + 8192); \
    GLD16(gb_ + 128 * SS, (lb) + 16384); \
    GLD16(gb_ + 192 * SS, (lb) + 24576); }

#define LDA2(Ab_, mh, kx) { \
    const char* p_ = (const char*)(Ab_) + aRow + (mh) * 4096 + ((kx) ? (cx0 ^ 64) : cx0); \
    fa0 = *(const bf16x8*)(p_); \
    fa1 = *(const bf16x8*)(p_ + 2048); }

#define LDB4(Bb_, kx) { \
    const char* p_ = (const char*)(Bb_) + bRow + ((kx) ? (cx0 ^ 64) : cx0); \
    fb0 = *(const bf16x8*)(p_); \
    fb1 = *(const bf16x8*)(p_ + 2048); \
    fb2 = *(const bf16x8*)(p_ + 4096); \
    fb3 = *(const bf16x8*)(p_ + 6144); }

#define MROWP(mi, fa) \
    acc[mi][0] = __builtin_amdgcn_mfma_f32_16x16x32_bf16(fa, fb0, acc[mi][0],0,0,0); \
    acc[mi][1] = __builtin_amdgcn_mfma_f32_16x16x32_bf16(fa, fb1, acc[mi][1],0,0,0); \
    acc[mi][2] = __builtin_amdgcn_mfma_f32_16x16x32_bf16(fa, fb2, acc[mi][2],0,0,0); \
    acc[mi][3] = __builtin_amdgcn_mfma_f32_16x16x32_bf16(fa, fb3, acc[mi][3],0,0,0);

    STAGE_PV(0, lA0, lB0);
    STAGE_PV(1, lA1, lB1);
    asm volatile("s_waitcnt vmcnt(6)" ::: "memory");
    SCHED0(); __builtin_amdgcn_s_barrier(); SCHED0();

#pragma unroll 1
    for (int it = 0; it < 16; ++it){
        bf16x8 fa0, fa1, fb0, fb1, fb2, fb3;
        // K-tile 2it from buf0
        LDA2(As[0], 0, 0); LDB4(Bs[0], 0);
        PH_PRE(); MROWP(0,fa0) MROWP(1,fa1) PH_POST();
        LDA2(As[0], 1, 0);
        PH_PRE(); MROWP(2,fa0) MROWP(3,fa1) PH_POST();
        LDA2(As[0], 0, 1); LDB4(Bs[0], 1);
        PH_PRE(); MROWP(0,fa0) MROWP(1,fa1) PH_POST();
        LDA2(As[0], 1, 1);
        PH_PRE(); MROWP(2,fa0) MROWP(3,fa1) PH_POST();
        if (it < 15){
            STAGE_PV(2*it+2, lA0, lB0);
            asm volatile("s_waitcnt vmcnt(6)" ::: "memory");
        } else {
            asm volatile("s_waitcnt vmcnt(0)" ::: "memory");
        }
        SCHED0(); __builtin_amdgcn_s_barrier(); SCHED0();
        // K-tile 2it+1 from buf1
        LDA2(As[1], 0, 0); LDB4(Bs[1], 0);
        PH_PRE(); MROWP(0,fa0) MROWP(1,fa1) PH_POST();
        LDA2(As[1], 1, 0);
        PH_PRE(); MROWP(2,fa0) MROWP(3,fa1) PH_POST();
        LDA2(As[1], 0, 1); LDB4(Bs[1], 1);
        PH_PRE(); MROWP(0,fa0) MROWP(1,fa1) PH_POST();
        LDA2(As[1], 1, 1);
        PH_PRE(); MROWP(2,fa0) MROWP(3,fa1) PH_POST();
        if (it < 15){
            STAGE_PV(2*it+3, lA1, lB1);
            asm volatile("s_waitcnt vmcnt(6)" ::: "memory");
            SCHED0(); __builtin_amdgcn_s_barrier(); SCHED0();
        }
    }
#undef STAGE_PV
#undef LDA2
#undef LDB4
#undef MROWP

#pragma unroll
    for (int m = 0; m < 4; ++m){
        float inv[4];
#pragma unroll
        for (int r = 0; r < 4; ++r)
            inv[r] = 1.f / rowsum[b * SS + row0 + wr * 64 + m * 16 + g4 * 4 + r];
#pragma unroll
        for (int n = 0; n < 4; ++n){
            const int gcol = col0 + wc * 64 + n * 16 + l16;
#pragma unroll
            for (int r = 0; r < 4; ++r){
                const int grow = row0 + wr * 64 + m * 16 + g4 * 4 + r;
                Xn[(size_t)(b * SS + grow) * DD + gcol] = f2bf(acc[m][n][r] * inv[r]);
            }
        }
    }
}

// ---------------- pass 3: LayerNorm over d ----------------
__global__ __launch_bounds__(256) void ln_kernel(
    const u16* __restrict__ Xn, const float* __restrict__ gamma,
    const float* __restrict__ beta, float* __restrict__ out)
{
    __shared__ float red[2][4];
    const int row = blockIdx.x;      // b*S + s
    const int t = threadIdx.x;
    short4v xv = *(const short4v*)&Xn[(size_t)row * DD + t * 4];
    float x[4];
#pragma unroll
    for (int j = 0; j < 4; ++j)
        x[j] = __uint_as_float(((unsigned)(u16)xv[j]) << 16);
    float s  = x[0] + x[1] + x[2] + x[3];
    float sq = x[0]*x[0] + x[1]*x[1] + x[2]*x[2] + x[3]*x[3];
#pragma unroll
    for (int d = 1; d < 64; d <<= 1){ s += __shfl_xor(s, d); sq += __shfl_xor(sq, d); }
    const int wv = t >> 6;
    if ((t & 63) == 0){ red[0][wv] = s; red[1][wv] = sq; }
    __syncthreads();
    float S  = red[0][0] + red[0][1] + red[0][2] + red[0][3];
    float Sq = red[1][0] + red[1][1] + red[1][2] + red[1][3];
    float mu = S * (1.f / 1024.f);
    float var = Sq * (1.f / 1024.f) - mu * mu;
    float rstd = rsqrtf(var + 1e-5f);
    float4v g  = *(const float4v*)&gamma[t * 4];
    float4v be = *(const float4v*)&beta[t * 4];
    float4v o;
#pragma unroll
    for (int j = 0; j < 4; ++j) o[j] = (x[j] - mu) * rstd * g[j] + be[j];
    *(float4v*)&out[(size_t)row * DD + t * 4] = o;
}

extern "C" void kernel_launch(void* const* d_in, const int* in_sizes, int n_in,
                              void* d_out, int out_size, void* d_ws, size_t ws_size,
                              hipStream_t stream) {
    const float* q     = (const float*)d_in[0];
    const float* k     = (const float*)d_in[1];
    const float* v     = (const float*)d_in[2];
    const int*   mask  = (const int*)d_in[3];
    const float* gamma = (const float*)d_in[4];
    const float* beta  = (const float*)d_in[5];
    float* out = (float*)d_out;

    u16* Qb = (u16*)d_ws;                                  // 16 MB (pre-scaled by 1/sqrt(d))
    u16* Kb = Qb + (size_t)BB * SS * DD;                   // 16 MB
    u16* Vt = Kb + (size_t)BB * SS * DD;                   // 16 MB
    u16* P  = Vt + (size_t)BB * SS * DD;                   // 32 MB
    u16* Xn = P  + (size_t)BB * SS * SS;                   // 16 MB
    float* rowsum = (float*)(Xn + (size_t)BB * SS * DD);   // 32 KB

    const int n4 = BB * SS * DD / 4;
    conv_bf16_kernel<<<n4 / 256, 256, 0, stream>>>(q, Qb, n4, 0.03125f);
    conv_bf16_kernel<<<n4 / 256, 256, 0, stream>>>(k, Kb, n4, 1.0f);
    transpose_v_kernel<<<dim3(SS / 64, DD / 64, BB), 256, 0, stream>>>(v, Vt);
    zero_f32<<<BB * SS / 256, 256, 0, stream>>>(rowsum, BB * SS);

    qk_kernel<<<256, 512, 0, stream>>>(Qb, Kb, mask, P, rowsum);
    pv_kernel<<<256, 512, 0, stream>>>(P, Vt, rowsum, Xn);
    ln_kernel<<<BB * SS, 256, 0, stream>>>(Xn, gamma, beta, out);
}